// Round 2
// baseline (17535.338 us; speedup 1.0000x reference)
//
#include <hip/hip_runtime.h>
#include <math.h>

// LSTMDecoder: VOCAB=32000, EMB=512, HID=512, LAYERS=2, BATCH=32, SEQ=64
// Round 3: single persistent mega-kernel for the whole 64-step recurrence.
//  - grid=256 blocks (= CU count, co-resident by LDS/wave capacity), 256 thr.
//  - per step: [L0 gemm+ticket-cell] GBAR [L1 gemm+ticket-cell] GBAR [FC+argmax] GBAR
//  - global barrier = monotone atomic counter + threadfence acq_rel (wbl2+inv),
//    replacing 192 kernel boundaries (drain+dispatch+invalidate) with ~191 barriers.
//  - klstm/kfc phase bodies identical to the verified round-2 kernels; ticket
//    finisher kept (no early return so all blocks reach the barrier).

#define BB   32
#define EMBD 512
#define HIDD 512
#define VV   32000
#define SS   64
#define GJ   2048          // 4*HID
#define OST  (SS*VV)       // out stride per batch
#define NB   256           // mega-kernel grid size

__device__ __forceinline__ float sigf(float x){ return 1.0f/(1.0f + expf(-x)); }
__device__ __forceinline__ unsigned keyOf(float f){
  unsigned u = __float_as_uint(f);
  return (u & 0x80000000u) ? ~u : (u | 0x80000000u);   // monotone float->uint
}

// generic 32x32 tiled transpose: dst[c*dstLd + r] = src[r*C + c]
__global__ void ktran(const float* __restrict__ src, float* __restrict__ dst,
                      int R, int C, int dstLd)
{
  __shared__ float t[32][33];
  int c0 = blockIdx.x*32, r0 = blockIdx.y*32;
  int tx = threadIdx.x & 31, ty = threadIdx.x >> 5;
  #pragma unroll
  for (int i=0;i<4;i++) t[ty+i*8][tx] = src[(size_t)(r0+ty+i*8)*C + (c0+tx)];
  __syncthreads();
  #pragma unroll
  for (int i=0;i<4;i++) dst[(size_t)(c0+ty+i*8)*dstLd + (r0+tx)] = t[tx][ty+i*8];
}

__global__ void kbias(const float* __restrict__ bih, const float* __restrict__ bhh,
                      float* __restrict__ bias2){
  int i = blockIdx.x*256 + threadIdx.x;
  if (i < 2*GJ) bias2[i] = bih[i] + bhh[i];
}

// x0T[k][b] = input_seq[b][0][k];  hT/cT parity0: [l][u][b] = h_encode[l][b][u]
__global__ void kinit(const float* __restrict__ iseq, const float* __restrict__ he,
                      const float* __restrict__ ce, float* __restrict__ x0T,
                      float* __restrict__ hT, float* __restrict__ cT)
{
  int tid = blockIdx.x*256 + threadIdx.x;
  if (tid < 16384){
    int k = tid>>5, b = tid&31;
    x0T[tid] = iseq[(size_t)b*(SS*EMBD) + k];
  } else if (tid < 49152){
    int t2 = tid - 16384;
    int l = t2>>14, r = t2&16383, u = r>>5, b = r&31;
    hT[t2] = he[(size_t)(l*BB + b)*HIDD + u];
  } else if (tid < 81920){
    int t2 = tid - 49152;
    int l = t2>>14, r = t2&16383, u = r>>5, b = r&31;
    cT[t2] = ce[(size_t)(l*BB + b)*HIDD + u];
  }
}

// Global barrier: monotone counter, no reset (replay-safe via host memset).
// Release: __threadfence before arrival (wbl2). Acquire: __threadfence after
// spin (inv) so cross-step stale L2 lines are discarded.
__device__ __forceinline__ void gbar(unsigned* bar, unsigned target){
  __syncthreads();
  __threadfence();
  if (threadIdx.x == 0){
    __hip_atomic_fetch_add(bar, 1u, __ATOMIC_RELAXED, __HIP_MEMORY_SCOPE_AGENT);
    while (__hip_atomic_load(bar, __ATOMIC_RELAXED, __HIP_MEMORY_SCOPE_AGENT) < target)
      __builtin_amdgcn_s_sleep(2);
  }
  __syncthreads();
  __threadfence();
}

__global__ __launch_bounds__(256) void kmega(
    const float* __restrict__ W2T, const float* __restrict__ bias2,
    const float* __restrict__ x0T, const float* __restrict__ emb,
    const float* __restrict__ fcWT, const float* __restrict__ fcb,
    float* __restrict__ hT, float* __restrict__ cT,
    float* __restrict__ partL0, float* __restrict__ partL1,
    unsigned long long* __restrict__ slots, unsigned* __restrict__ ctr,
    unsigned* __restrict__ barcnt, float* __restrict__ out)
{
  __shared__ float smem[12576];   // 50.3KB: lstm{xg 4096, red 8320} / fc{part 8448, fin 4128}
  __shared__ int isLast;
  const int bx = blockIdx.x, tid = threadIdx.x, lane = tid & 63, kc = tid >> 6;
  const size_t LSZ = (size_t)512*BB;
  unsigned bt = 0;

  for (int s=0; s<SS; s++){
    const int p = s & 1, q = p ^ 1;

    // ================= LSTM layers =================
    for (int l=0; l<2; l++){
      const float* Wl   = W2T + (size_t)l*1024*GJ;
      const float* bl   = bias2 + l*GJ;
      const float* hsrc = hT + (size_t)(p*2+l)*LSZ;
      const float* csrc = cT + (size_t)(p*2+l)*LSZ;
      float* hdst = hT + (size_t)(q*2+l)*LSZ;
      float* cdst = cT + (size_t)(q*2+l)*LSZ;
      float* part = l ? partL1 : partL0;
      unsigned* ct = ctr + l*8;
      const int use_emb = (l==0 && s>0);
      const float* xsrc = l ? (hT + (size_t)(q*2+0)*LSZ) : x0T;   // layer1 x = h0d
      const unsigned long long* slp = slots + (size_t)((s+1)&1)*BB; // == parity (s-1)&1

      float* xg  = smem;          // [128k][32b]
      float* red = smem + 4096;   // [4*32][65]
      const int jt = bx & 31, ko = bx >> 5;
      const int j = jt*64 + lane;

      // ---- stage activation chunk into LDS ----
      if (ko >= 4){                                   // recurrent half: h chunk
        const float* base = hsrc + (size_t)(ko-4)*128*BB;
        #pragma unroll
        for (int i=0;i<4;i++)
          *(float4*)&xg[(i*256+tid)*4] = *(const float4*)(base + (size_t)(i*256+tid)*4);
      } else if (!use_emb){                           // x chunk (x0T or prev-layer hT)
        const float* base = xsrc + (size_t)ko*128*BB;
        #pragma unroll
        for (int i=0;i<4;i++)
          *(float4*)&xg[(i*256+tid)*4] = *(const float4*)(base + (size_t)(i*256+tid)*4);
      } else {                                        // x = emb[argmax(prev)] gather
        int gb = tid & 31, kt = tid >> 5;             // 32 b x 8 kt (16 k each)
        unsigned long long pk = slp[gb];
        unsigned idx = 0xFFFFFFFFu - (unsigned)(pk & 0xFFFFFFFFull);
        const float* row = emb + (size_t)idx*EMBD + ko*128 + kt*16;
        #pragma unroll
        for (int q4=0;q4<4;q4++){
          float4 r4 = *(const float4*)(row + q4*4);
          xg[(kt*16+q4*4+0)*32 + gb] = r4.x;
          xg[(kt*16+q4*4+1)*32 + gb] = r4.y;
          xg[(kt*16+q4*4+2)*32 + gb] = r4.z;
          xg[(kt*16+q4*4+3)*32 + gb] = r4.w;
        }
      }
      __syncthreads();

      // ---- GEMM: 32 k-iters, LDS broadcast activations ----
      float acc[BB];
      #pragma unroll
      for (int b=0;b<BB;b++) acc[b] = 0.f;

      const float* wp = Wl + (size_t)(ko*128 + kc*32)*GJ + j;
      const float* xb = &xg[(kc*32)*32];
      for (int kk=0;kk<32;kk++){
        float w = wp[(size_t)kk*GJ];                  // coalesced over j
        const float* xr = xb + kk*32;                 // same addr all lanes: broadcast
        #pragma unroll
        for (int bq=0;bq<8;bq++){
          float4 xa = *(const float4*)(xr + bq*4);
          acc[bq*4+0] = fmaf(xa.x, w, acc[bq*4+0]);
          acc[bq*4+1] = fmaf(xa.y, w, acc[bq*4+1]);
          acc[bq*4+2] = fmaf(xa.z, w, acc[bq*4+2]);
          acc[bq*4+3] = fmaf(xa.w, w, acc[bq*4+3]);
        }
      }

      #pragma unroll
      for (int b=0;b<BB;b++) red[(kc*32+b)*65 + lane] = acc[b];
      __syncthreads();

      // ---- reduce 4 kc partials, store part[ko][j][b] fully coalesced ----
      #pragma unroll
      for (int i=0;i<8;i++){
        int idx = i*256 + tid, jl = idx >> 5, b2 = idx & 31;
        float v = red[(0*32+b2)*65 + jl] + red[(1*32+b2)*65 + jl]
                + red[(2*32+b2)*65 + jl] + red[(3*32+b2)*65 + jl];
        part[((size_t)ko*GJ + jt*64 + jl)*BB + b2] = v;
      }
      __threadfence();            // release partials device-wide
      __syncthreads();
      const int ug = jt & 7;      // unit group: 64 units <- jt in {ug,ug+8,ug+16,ug+24}
      if (tid == 0) isLast = (atomicAdd(&ct[ug], 1u) == 31u);
      __syncthreads();
      if (isLast){
        if (tid == 0) ct[ug] = 0; // re-arm for next step
        __threadfence();          // acquire partials
        const int u0 = ug*64;
        for (int i=0;i<8;i++){
          int cid = i*256 + tid;
          int u = cid >> 5, b2 = cid & 31;
          int uu = u0 + u;
          float gi=0.f, gf=0.f, gg=0.f, go=0.f;
          #pragma unroll
          for (int k2=0;k2<8;k2++){
            const float* pp = part + (size_t)k2*GJ*BB;  // coalesced: b on lanes
            gi += pp[(size_t)(0*512+uu)*BB + b2];
            gf += pp[(size_t)(1*512+uu)*BB + b2];
            gg += pp[(size_t)(2*512+uu)*BB + b2];
            go += pp[(size_t)(3*512+uu)*BB + b2];
          }
          gi += bl[uu]; gf += bl[512+uu]; gg += bl[1024+uu]; go += bl[1536+uu];
          float co = csrc[uu*BB + b2];
          float cn = sigf(gf)*co + sigf(gi)*tanhf(gg);
          float hn = sigf(go)*tanhf(cn);
          cdst[uu*BB + b2] = cn;
          hdst[uu*BB + b2] = hn;
        }
      }
      bt += NB; gbar(barcnt, bt);
    }

    // ================= FC + argmax =================
    {
      const float* h1T = hT + (size_t)(q*2+1)*LSZ;
      unsigned long long* slots_cur  = slots + (size_t)(s&1)*BB;
      unsigned long long* slots_next = slots + (size_t)((s+1)&1)*BB;

      if (bx < 250){
        float* partA = smem;           // [2][128*33]
        float* fin   = smem + 8448;    // [32][129]
        const int c0 = lane*2;
        const int v0 = bx*128 + c0;

        float acc0[BB], acc1[BB];
        #pragma unroll
        for (int b=0;b<BB;b++){ acc0[b] = 0.f; acc1[b] = 0.f; }

        const float2* wp = (const float2*)(fcWT + (size_t)(kc*128)*VV) + (v0 >> 1);
        const float*  hb = h1T + kc*128*BB;
        for (int kk=0;kk<128;kk++){
          float2 w = wp[(size_t)kk*(VV/2)];             // 512B/wave, coalesced over v
          const float* xr = hb + kk*BB;                 // wave-uniform broadcast
          #pragma unroll
          for (int bq=0;bq<8;bq++){
            float4 xa = *(const float4*)(xr + bq*4);
            acc0[bq*4+0] = fmaf(xa.x, w.x, acc0[bq*4+0]);
            acc1[bq*4+0] = fmaf(xa.x, w.y, acc1[bq*4+0]);
            acc0[bq*4+1] = fmaf(xa.y, w.x, acc0[bq*4+1]);
            acc1[bq*4+1] = fmaf(xa.y, w.y, acc1[bq*4+1]);
            acc0[bq*4+2] = fmaf(xa.z, w.x, acc0[bq*4+2]);
            acc1[bq*4+2] = fmaf(xa.z, w.y, acc1[bq*4+2]);
            acc0[bq*4+3] = fmaf(xa.w, w.x, acc0[bq*4+3]);
            acc1[bq*4+3] = fmaf(xa.w, w.y, acc1[bq*4+3]);
          }
        }

        // 2-phase k-reduction in LDS (kc0/1 write, kc2/3 add)
        if (kc < 2){
          float* pp = partA + kc*(128*33);
          #pragma unroll
          for (int b=0;b<BB;b++){ pp[(c0+0)*33 + b] = acc0[b]; pp[(c0+1)*33 + b] = acc1[b]; }
        }
        __syncthreads();
        if (kc >= 2){
          float* pp = partA + (kc-2)*(128*33);
          #pragma unroll
          for (int b=0;b<BB;b++){ pp[(c0+0)*33 + b] += acc0[b]; pp[(c0+1)*33 + b] += acc1[b]; }
        }
        __syncthreads();

        // epilogue: bias, out write (coalesced over v), fin for argmax
        #pragma unroll
        for (int i=0;i<16;i++){
          int cl = (tid & 63) + 64*(i & 1);
          int b  = (tid >> 6) + 4*(i >> 1);
          float val = partA[cl*33 + b] + partA[128*33 + cl*33 + b] + fcb[bx*128 + cl];
          out[(size_t)b*OST + (size_t)s*VV + bx*128 + cl] = val;
          fin[b*129 + cl] = val;
        }
        __syncthreads();

        if (tid < 32){
          int b = tid;
          float best = fin[b*129]; int bv = 0;
          for (int c=1; c<128; c++){                    // ascending: first max wins
            float f = fin[b*129 + c];
            if (f > best){ best = f; bv = c; }
          }
          unsigned long long pk = ((unsigned long long)keyOf(best) << 32)
                                | (unsigned long long)(0xFFFFFFFFu - (unsigned)(bx*128 + bv));
          unsigned long long cur = slots_cur[b];        // guard read (perf only; safe)
          if (pk > cur) atomicMax(slots_cur + b, pk);
        }
      }
      if (bx == 0 && tid >= 64 && tid < 96) slots_next[tid - 64] = 0ull;
    }
    if (s < SS-1){ bt += NB; gbar(barcnt, bt); }
  }
}

extern "C" void kernel_launch(void* const* d_in, const int* in_sizes, int n_in,
                              void* d_out, int out_size, void* d_ws, size_t ws_size,
                              hipStream_t stream)
{
  const float* input_seq = (const float*)d_in[0];
  const float* h_enc     = (const float*)d_in[1];
  const float* c_enc     = (const float*)d_in[2];
  const float* Wih       = (const float*)d_in[3];
  const float* Whh       = (const float*)d_in[4];
  const float* bih       = (const float*)d_in[5];
  const float* bhh       = (const float*)d_in[6];
  const float* fcW       = (const float*)d_in[7];
  const float* fcb       = (const float*)d_in[8];
  const float* emb       = (const float*)d_in[9];
  float* out = (float*)d_out;

  char* ws = (char*)d_ws;
  size_t off = 0;
  auto alloc = [&](size_t bytes)->void*{
    void* p = ws + off; off += (bytes + 255) & ~(size_t)255; return p;
  };
  float* fcWT  = (float*)alloc((size_t)512*VV*4);        // [k][v]
  float* W2T   = (float*)alloc((size_t)2*1024*GJ*4);     // [l][k][j]
  float* bias2 = (float*)alloc((size_t)2*GJ*4);
  float* x0T   = (float*)alloc((size_t)512*BB*4);        // [k][b]
  float* hT    = (float*)alloc((size_t)2*2*512*BB*4);    // [parity][l][u][b]
  float* cT    = (float*)alloc((size_t)2*2*512*BB*4);
  float* partL0= (float*)alloc((size_t)8*GJ*BB*4);       // [ko][j][b]
  float* partL1= (float*)alloc((size_t)8*GJ*BB*4);
  unsigned long long* slots = (unsigned long long*)alloc(2*BB*8); // [parity][b]
  unsigned* ctr    = (unsigned*)alloc(16*4);             // [layer][ug]
  unsigned* barcnt = (unsigned*)alloc(4);                // global barrier counter

  hipMemsetAsync(slots, 0, 2*BB*8, stream);
  hipMemsetAsync(ctr,   0, 16*4,   stream);
  hipMemsetAsync(barcnt,0, 4,      stream);

  dim3 tb(256);
  ktran<<<dim3(16,1000), tb, 0, stream>>>(fcW, fcWT, VV, 512, VV);
  ktran<<<dim3(16,64), tb, 0, stream>>>(Wih,            W2T,                         GJ, 512, GJ);
  ktran<<<dim3(16,64), tb, 0, stream>>>(Whh,            W2T + (size_t)512*GJ,        GJ, 512, GJ);
  ktran<<<dim3(16,64), tb, 0, stream>>>(Wih + (size_t)GJ*512, W2T + (size_t)1024*GJ, GJ, 512, GJ);
  ktran<<<dim3(16,64), tb, 0, stream>>>(Whh + (size_t)GJ*512, W2T + (size_t)1024*GJ + (size_t)512*GJ, GJ, 512, GJ);
  kbias<<<16, tb, 0, stream>>>(bih, bhh, bias2);
  kinit<<<320, tb, 0, stream>>>(input_seq, h_enc, c_enc, x0T, hT, cT);

  kmega<<<NB, tb, 0, stream>>>(W2T, bias2, x0T, emb, fcWT, fcb,
                               hT, cT, partL0, partL1, slots, ctr, barcnt, out);
}

// Round 3
// 10430.678 us; speedup vs baseline: 1.6811x; 1.6811x over previous
//
#include <hip/hip_runtime.h>
#include <math.h>

// LSTMDecoder: VOCAB=32000, EMB=512, HID=512, LAYERS=2, BATCH=32, SEQ=64
// Round 4: launched structure (verified r2 @8483us) + 2x wave parallelism.
//  - klstm: block=512 (8 waves/CU vs 4), k-split 8x16, 2-phase LDS reduction
//    (4 slabs, 49.3KB). Grid 256. Ticket finisher unchanged.
//  - kfc: block=512, k-split 8x64, 4-phase pairwise LDS reduction into 2 slabs
//    (50.3KB). Grid 250. Weight loads unrolled for MLP.
//  - Mega-kernel experiment (r3: 17.5ms, VALUBusy 3.9%) refuted: phases are
//    latency-bound; kernel boundaries give free inter-phase overlap. Reverted.

#define BB   32
#define EMBD 512
#define HIDD 512
#define VV   32000
#define SS   64
#define GJ   2048          // 4*HID
#define OST  (SS*VV)       // out stride per batch

__device__ __forceinline__ float sigf(float x){ return 1.0f/(1.0f + expf(-x)); }
__device__ __forceinline__ unsigned keyOf(float f){
  unsigned u = __float_as_uint(f);
  return (u & 0x80000000u) ? ~u : (u | 0x80000000u);   // monotone float->uint
}

// generic 32x32 tiled transpose: dst[c*dstLd + r] = src[r*C + c]
__global__ void ktran(const float* __restrict__ src, float* __restrict__ dst,
                      int R, int C, int dstLd)
{
  __shared__ float t[32][33];
  int c0 = blockIdx.x*32, r0 = blockIdx.y*32;
  int tx = threadIdx.x & 31, ty = threadIdx.x >> 5;
  #pragma unroll
  for (int i=0;i<4;i++) t[ty+i*8][tx] = src[(size_t)(r0+ty+i*8)*C + (c0+tx)];
  __syncthreads();
  #pragma unroll
  for (int i=0;i<4;i++) dst[(size_t)(c0+ty+i*8)*dstLd + (r0+tx)] = t[tx][ty+i*8];
}

__global__ void kbias(const float* __restrict__ bih, const float* __restrict__ bhh,
                      float* __restrict__ bias2){
  int i = blockIdx.x*256 + threadIdx.x;
  if (i < 2*GJ) bias2[i] = bih[i] + bhh[i];
}

// x0T[k][b] = input_seq[b][0][k];  hT/cT parity0: [l][u][b] = h_encode[l][b][u]
__global__ void kinit(const float* __restrict__ iseq, const float* __restrict__ he,
                      const float* __restrict__ ce, float* __restrict__ x0T,
                      float* __restrict__ hT, float* __restrict__ cT)
{
  int tid = blockIdx.x*256 + threadIdx.x;
  if (tid < 16384){
    int k = tid>>5, b = tid&31;
    x0T[tid] = iseq[(size_t)b*(SS*EMBD) + k];
  } else if (tid < 49152){
    int t2 = tid - 16384;
    int l = t2>>14, r = t2&16383, u = r>>5, b = r&31;
    hT[t2] = he[(size_t)(l*BB + b)*HIDD + u];
  } else if (tid < 81920){
    int t2 = tid - 49152;
    int l = t2>>14, r = t2&16383, u = r>>5, b = r&31;
    cT[t2] = ce[(size_t)(l*BB + b)*HIDD + u];
  }
}

// One LSTM layer. grid=256: jt=bx&31 (64-wide j tile), ko=bx>>5 (128-wide k chunk
// of K=1024=[x(512);h(512)]). block=512=8 waves (kc: 16-wide k subchunk).
// Activation chunk staged in LDS; inner reads are wave-uniform broadcasts.
// Partials -> part[ko][j][b] (coalesced both ways); ticket finisher does cell.
__global__ __launch_bounds__(512) void klstm(
    const float* __restrict__ W2T, const float* __restrict__ bias2,
    const float* __restrict__ xsrc, const unsigned long long* __restrict__ slots_prev,
    const float* __restrict__ emb,
    const float* __restrict__ hsrc, const float* __restrict__ csrc,
    float* __restrict__ hdst, float* __restrict__ cdst,
    float* __restrict__ part, unsigned* __restrict__ ctr, int use_emb)
{
  __shared__ float xg[128*32];      // block's 128-k x 32-b activation chunk (16KB)
  __shared__ float red[4*32*65];    // 4 slabs [b][j], pad 65 (33.3KB)
  __shared__ int isLast;
  int bx = blockIdx.x;
  int jt = bx & 31, ko = bx >> 5;
  int tid = threadIdx.x, lane = tid & 63, kc = tid >> 6;   // kc in [0,8)
  int j = jt*64 + lane;

  // ---- stage activation chunk into LDS ----
  if (ko >= 4){                                   // recurrent half: h chunk
    const float* base = hsrc + (size_t)(ko-4)*128*BB;
    #pragma unroll
    for (int i=0;i<2;i++)
      *(float4*)&xg[(i*512+tid)*4] = *(const float4*)(base + (size_t)(i*512+tid)*4);
  } else if (!use_emb){                           // x chunk (x0T or prev-layer hT)
    const float* base = xsrc + (size_t)ko*128*BB;
    #pragma unroll
    for (int i=0;i<2;i++)
      *(float4*)&xg[(i*512+tid)*4] = *(const float4*)(base + (size_t)(i*512+tid)*4);
  } else {                                        // x = emb[argmax(prev)] gather
    int gb = tid & 31, kt = tid >> 5;             // 32 b x 16 kt (8 k each)
    unsigned long long pk = slots_prev[gb];
    unsigned idx = 0xFFFFFFFFu - (unsigned)(pk & 0xFFFFFFFFull);
    const float* row = emb + (size_t)idx*EMBD + ko*128 + kt*8;
    #pragma unroll
    for (int q=0;q<2;q++){
      float4 r4 = *(const float4*)(row + q*4);
      xg[(kt*8+q*4+0)*32 + gb] = r4.x;
      xg[(kt*8+q*4+1)*32 + gb] = r4.y;
      xg[(kt*8+q*4+2)*32 + gb] = r4.z;
      xg[(kt*8+q*4+3)*32 + gb] = r4.w;
    }
  }
  __syncthreads();

  // ---- GEMM: 16 k-iters (full unroll -> all weight loads in flight) ----
  float acc[BB];
  #pragma unroll
  for (int b=0;b<BB;b++) acc[b] = 0.f;

  const float* wp = W2T + (size_t)(ko*128 + kc*16)*GJ + j;
  const float* xb = &xg[(kc*16)*32];
  #pragma unroll
  for (int kk=0;kk<16;kk++){
    float w = wp[(size_t)kk*GJ];                  // coalesced over j
    const float* xr = xb + kk*32;                 // same addr all lanes: broadcast
    #pragma unroll
    for (int bq=0;bq<8;bq++){
      float4 xa = *(const float4*)(xr + bq*4);
      acc[bq*4+0] = fmaf(xa.x, w, acc[bq*4+0]);
      acc[bq*4+1] = fmaf(xa.y, w, acc[bq*4+1]);
      acc[bq*4+2] = fmaf(xa.z, w, acc[bq*4+2]);
      acc[bq*4+3] = fmaf(xa.w, w, acc[bq*4+3]);
    }
  }

  // ---- 2-phase reduction: kc<4 write slab kc, kc>=4 add slab kc-4 ----
  if (kc < 4){
    #pragma unroll
    for (int b=0;b<BB;b++) red[(kc*32+b)*65 + lane] = acc[b];
  }
  __syncthreads();
  if (kc >= 4){
    #pragma unroll
    for (int b=0;b<BB;b++) red[((kc-4)*32+b)*65 + lane] += acc[b];
  }
  __syncthreads();

  // ---- sum 4 slabs, store part[ko][j][b] fully coalesced ----
  #pragma unroll
  for (int i=0;i<4;i++){
    int idx = i*512 + tid, jl = idx >> 5, b2 = idx & 31;
    float v = red[(0*32+b2)*65 + jl] + red[(1*32+b2)*65 + jl]
            + red[(2*32+b2)*65 + jl] + red[(3*32+b2)*65 + jl];
    part[((size_t)ko*GJ + jt*64 + jl)*BB + b2] = v;
  }
  __threadfence();            // release partials device-wide
  __syncthreads();
  int ug = jt & 7;            // unit group: 64 units <- jt in {ug,ug+8,ug+16,ug+24}
  if (tid == 0) isLast = (atomicAdd(&ctr[ug], 1u) == 31u);
  __syncthreads();
  if (!isLast) return;

  if (tid == 0) ctr[ug] = 0;  // re-arm for next launch
  __threadfence();            // acquire (kernel also starts w/ acquire next launch)
  const int u0 = ug*64;
  for (int i=0;i<4;i++){
    int cid = i*512 + tid;
    int u = cid >> 5, b2 = cid & 31;
    int uu = u0 + u;
    float gi=0.f, gf=0.f, gg=0.f, go=0.f;
    #pragma unroll
    for (int k2=0;k2<8;k2++){
      const float* pp = part + (size_t)k2*GJ*BB;  // coalesced: b on lanes
      gi += pp[(size_t)(0*512+uu)*BB + b2];
      gf += pp[(size_t)(1*512+uu)*BB + b2];
      gg += pp[(size_t)(2*512+uu)*BB + b2];
      go += pp[(size_t)(3*512+uu)*BB + b2];
    }
    gi += bias2[uu]; gf += bias2[512+uu]; gg += bias2[1024+uu]; go += bias2[1536+uu];
    float co = csrc[uu*BB + b2];
    float cn = sigf(gf)*co + sigf(gi)*tanhf(gg);
    float hn = sigf(go)*tanhf(cn);
    cdst[uu*BB + b2] = cn;
    hdst[uu*BB + b2] = hn;
  }
}

// FC + argmax. grid=250 (128-col tiles), block=512=8 waves.
// Lane owns 2 cols (float2 weights); kc=tid>>6 is a 64-k split; h broadcast via
// wave-uniform global float4 (1 txn/instr). 4-phase pairwise LDS reduction.
__global__ __launch_bounds__(512) void kfc(
    const float* __restrict__ fcWT, const float* __restrict__ fcb,
    const float* __restrict__ h1T, float* __restrict__ out, int s,
    unsigned long long* __restrict__ slots_cur,
    unsigned long long* __restrict__ slots_next)
{
  __shared__ float part[2][128*33];   // [pb][c][b], pad 33 (33.8KB)
  __shared__ float fin[32*129];       // [b][c], pad 129 (16.5KB)
  int bx = blockIdx.x;
  int tid = threadIdx.x, lane = tid & 63, kc = tid >> 6;   // kc in [0,8)
  int c0 = lane*2;
  int v0 = bx*128 + c0;

  float acc0[BB], acc1[BB];
  #pragma unroll
  for (int b=0;b<BB;b++){ acc0[b] = 0.f; acc1[b] = 0.f; }

  const float2* wp = (const float2*)(fcWT + (size_t)(kc*64)*VV) + (v0 >> 1);
  const float*  hb = h1T + kc*64*BB;
  #pragma unroll 8
  for (int kk=0;kk<64;kk++){
    float2 w = wp[(size_t)kk*(VV/2)];             // 512B/wave, coalesced over v
    const float* xr = hb + kk*BB;                 // wave-uniform: 1 txn per float4
    #pragma unroll
    for (int bq=0;bq<8;bq++){
      float4 xa = *(const float4*)(xr + bq*4);
      acc0[bq*4+0] = fmaf(xa.x, w.x, acc0[bq*4+0]);
      acc1[bq*4+0] = fmaf(xa.x, w.y, acc1[bq*4+0]);
      acc0[bq*4+1] = fmaf(xa.y, w.x, acc0[bq*4+1]);
      acc1[bq*4+1] = fmaf(xa.y, w.y, acc1[bq*4+1]);
      acc0[bq*4+2] = fmaf(xa.z, w.x, acc0[bq*4+2]);
      acc1[bq*4+2] = fmaf(xa.z, w.y, acc1[bq*4+2]);
      acc0[bq*4+3] = fmaf(xa.w, w.x, acc0[bq*4+3]);
      acc1[bq*4+3] = fmaf(xa.w, w.y, acc1[bq*4+3]);
    }
  }

  // 4-phase pairwise k-reduction into 2 slabs (kc0/1 write; 2/3, 4/5, 6/7 add)
  if (kc < 2){
    float* p = &part[kc][0];
    #pragma unroll
    for (int b=0;b<BB;b++){ p[(c0+0)*33 + b] = acc0[b]; p[(c0+1)*33 + b] = acc1[b]; }
  }
  __syncthreads();
  #pragma unroll
  for (int ph=1; ph<4; ph++){
    if ((kc >> 1) == ph){
      float* p = &part[kc & 1][0];
      #pragma unroll
      for (int b=0;b<BB;b++){ p[(c0+0)*33 + b] += acc0[b]; p[(c0+1)*33 + b] += acc1[b]; }
    }
    __syncthreads();
  }

  // epilogue: bias, out write (coalesced over v), fin for argmax
  #pragma unroll
  for (int i=0;i<8;i++){
    int cl = (tid & 63) + 64*(i & 1);
    int b  = (tid >> 6) + 8*(i >> 1);
    float val = part[0][cl*33 + b] + part[1][cl*33 + b] + fcb[bx*128 + cl];
    out[(size_t)b*OST + (size_t)s*VV + bx*128 + cl] = val;
    fin[b*129 + cl] = val;
  }
  __syncthreads();

  if (tid < 32){
    int b = tid;
    float best = fin[b*129]; int bv = 0;
    for (int c=1; c<128; c++){                    // ascending: first max wins
      float f = fin[b*129 + c];
      if (f > best){ best = f; bv = c; }
    }
    unsigned long long pk = ((unsigned long long)keyOf(best) << 32)
                          | (unsigned long long)(0xFFFFFFFFu - (unsigned)(bx*128 + bv));
    unsigned long long cur = slots_cur[b];        // guard read (perf only; safe)
    if (pk > cur) atomicMax(slots_cur + b, pk);
  }
  if (bx == 0 && tid >= 64 && tid < 96) slots_next[tid - 64] = 0ull;
}

extern "C" void kernel_launch(void* const* d_in, const int* in_sizes, int n_in,
                              void* d_out, int out_size, void* d_ws, size_t ws_size,
                              hipStream_t stream)
{
  const float* input_seq = (const float*)d_in[0];
  const float* h_enc     = (const float*)d_in[1];
  const float* c_enc     = (const float*)d_in[2];
  const float* Wih       = (const float*)d_in[3];
  const float* Whh       = (const float*)d_in[4];
  const float* bih       = (const float*)d_in[5];
  const float* bhh       = (const float*)d_in[6];
  const float* fcW       = (const float*)d_in[7];
  const float* fcb       = (const float*)d_in[8];
  const float* emb       = (const float*)d_in[9];
  float* out = (float*)d_out;

  char* ws = (char*)d_ws;
  size_t off = 0;
  auto alloc = [&](size_t bytes)->void*{
    void* p = ws + off; off += (bytes + 255) & ~(size_t)255; return p;
  };
  float* fcWT  = (float*)alloc((size_t)512*VV*4);        // [k][v]
  float* W2T   = (float*)alloc((size_t)2*1024*GJ*4);     // [l][k][j]
  float* bias2 = (float*)alloc((size_t)2*GJ*4);
  float* x0T   = (float*)alloc((size_t)512*BB*4);        // [k][b]
  float* hT    = (float*)alloc((size_t)2*2*512*BB*4);    // [parity][l][u][b]
  float* cT    = (float*)alloc((size_t)2*2*512*BB*4);
  float* partL0= (float*)alloc((size_t)8*GJ*BB*4);       // [ko][j][b]
  float* partL1= (float*)alloc((size_t)8*GJ*BB*4);
  unsigned long long* slots = (unsigned long long*)alloc(2*BB*8); // [parity][b]
  unsigned* ctr = (unsigned*)alloc(16*4);                // [layer][ug]

  hipMemsetAsync(slots, 0, 2*BB*8, stream);
  hipMemsetAsync(ctr,   0, 16*4,   stream);

  dim3 tb(256);
  dim3 tb2(512);
  ktran<<<dim3(16,1000), tb, 0, stream>>>(fcW, fcWT, VV, 512, VV);
  ktran<<<dim3(16,64), tb, 0, stream>>>(Wih,            W2T,                         GJ, 512, GJ);
  ktran<<<dim3(16,64), tb, 0, stream>>>(Whh,            W2T + (size_t)512*GJ,        GJ, 512, GJ);
  ktran<<<dim3(16,64), tb, 0, stream>>>(Wih + (size_t)GJ*512, W2T + (size_t)1024*GJ, GJ, 512, GJ);
  ktran<<<dim3(16,64), tb, 0, stream>>>(Whh + (size_t)GJ*512, W2T + (size_t)1024*GJ + (size_t)512*GJ, GJ, 512, GJ);
  kbias<<<16, tb, 0, stream>>>(bih, bhh, bias2);
  kinit<<<320, tb, 0, stream>>>(input_seq, h_enc, c_enc, x0T, hT, cT);

  const size_t LSZ = 512*BB;
  for (int s=0; s<SS; s++){
    int p = s & 1, q = p ^ 1;
    float* h0s = hT + (size_t)(p*2+0)*LSZ;  float* h0d = hT + (size_t)(q*2+0)*LSZ;
    float* h1s = hT + (size_t)(p*2+1)*LSZ;  float* h1d = hT + (size_t)(q*2+1)*LSZ;
    float* c0s = cT + (size_t)(p*2+0)*LSZ;  float* c0d = cT + (size_t)(q*2+0)*LSZ;
    float* c1s = cT + (size_t)(p*2+1)*LSZ;  float* c1d = cT + (size_t)(q*2+1)*LSZ;

    klstm<<<256, tb2, 0, stream>>>(W2T, bias2,
        (s==0) ? x0T : nullptr,
        (s>0) ? (slots + ((s-1)&1)*BB) : nullptr,
        emb, h0s, c0s, h0d, c0d, partL0, ctr, (s>0) ? 1 : 0);
    klstm<<<256, tb2, 0, stream>>>(W2T + (size_t)1024*GJ, bias2 + GJ,
        h0d, nullptr, emb, h1s, c1s, h1d, c1d, partL1, ctr + 8, 0);
    kfc<<<250, tb2, 0, stream>>>(fcWT, fcb, h1d, out, s,
        slots + (s&1)*BB, slots + ((s+1)&1)*BB);
  }
}

// Round 4
// 9378.284 us; speedup vs baseline: 1.8698x; 1.1122x over previous
//
#include <hip/hip_runtime.h>
#include <math.h>

// LSTMDecoder: VOCAB=32000, EMB=512, HID=512, LAYERS=2, BATCH=32, SEQ=64
// Round 5: one kernel per step (762 blocks), dataflow flags instead of 3 launches.
//  - bx[0,256): L0 (verified r2 body). bx[256,512): L1 -- h-half overlaps L0;
//    x-half spins on 2 L0-finisher flags. bx[512,762): FC spins on 8 L1 flags.
//  - Residency: 4 waves * 50.3KB LDS * VGPR<=170 (launch_bounds 256,3)
//    => 3 blocks/CU => all 762 resident; 384 non-waiting blocks guarantee progress.
//  - Flags monotone (s+1), release = stores;threadfence;syncthreads;tid0-store
//    (same pattern as the verified partials ticket). Per-step launches keep all
//    cross-step hazards behind kernel boundaries.
//  - r3 512-thread experiment refuted (10.4ms): TLP not the lever; reverted to
//    256-thread bodies verified at 8483us (r2) / numerically in merged form (r3-mega).

#define BB   32
#define EMBD 512
#define HIDD 512
#define VV   32000
#define SS   64
#define GJ   2048          // 4*HID
#define OST  (SS*VV)       // out stride per batch

__device__ __forceinline__ float sigf(float x){ return 1.0f/(1.0f + expf(-x)); }
__device__ __forceinline__ unsigned keyOf(float f){
  unsigned u = __float_as_uint(f);
  return (u & 0x80000000u) ? ~u : (u | 0x80000000u);   // monotone float->uint
}

// generic 32x32 tiled transpose: dst[c*dstLd + r] = src[r*C + c]
__global__ void ktran(const float* __restrict__ src, float* __restrict__ dst,
                      int R, int C, int dstLd)
{
  __shared__ float t[32][33];
  int c0 = blockIdx.x*32, r0 = blockIdx.y*32;
  int tx = threadIdx.x & 31, ty = threadIdx.x >> 5;
  #pragma unroll
  for (int i=0;i<4;i++) t[ty+i*8][tx] = src[(size_t)(r0+ty+i*8)*C + (c0+tx)];
  __syncthreads();
  #pragma unroll
  for (int i=0;i<4;i++) dst[(size_t)(c0+ty+i*8)*dstLd + (r0+tx)] = t[tx][ty+i*8];
}

__global__ void kbias(const float* __restrict__ bih, const float* __restrict__ bhh,
                      float* __restrict__ bias2){
  int i = blockIdx.x*256 + threadIdx.x;
  if (i < 2*GJ) bias2[i] = bih[i] + bhh[i];
}

// x0T[k][b] = input_seq[b][0][k];  hT/cT parity0: [l][u][b] = h_encode[l][b][u]
__global__ void kinit(const float* __restrict__ iseq, const float* __restrict__ he,
                      const float* __restrict__ ce, float* __restrict__ x0T,
                      float* __restrict__ hT, float* __restrict__ cT)
{
  int tid = blockIdx.x*256 + threadIdx.x;
  if (tid < 16384){
    int k = tid>>5, b = tid&31;
    x0T[tid] = iseq[(size_t)b*(SS*EMBD) + k];
  } else if (tid < 49152){
    int t2 = tid - 16384;
    int l = t2>>14, r = t2&16383, u = r>>5, b = r&31;
    hT[t2] = he[(size_t)(l*BB + b)*HIDD + u];
  } else if (tid < 81920){
    int t2 = tid - 49152;
    int l = t2>>14, r = t2&16383, u = r>>5, b = r&31;
    cT[t2] = ce[(size_t)(l*BB + b)*HIDD + u];
  }
}

// One decode step. grid=762, block=256=4 waves.
//  bx[0,256):   LSTM layer0  (jt=bx&31 j-tile, ko=bx>>5 k-chunk of 1024)
//  bx[256,512): LSTM layer1  (x-half ko<4 spins on L0f[2ko],L0f[2ko+1])
//  bx[512,762): FC+argmax    (spins on L1f[0..8))
__global__ __launch_bounds__(256, 3) void kstep(
    const float* __restrict__ W2T, const float* __restrict__ bias2,
    const float* __restrict__ x0T, const unsigned long long* __restrict__ slots_prev,
    const float* __restrict__ emb,
    const float* __restrict__ fcWT, const float* __restrict__ fcb,
    const float* h0s, const float* c0s, float* h0d, float* c0d,
    const float* h1s, const float* c1s, float* h1d, float* c1d,
    float* __restrict__ partL0, float* __restrict__ partL1,
    unsigned* __restrict__ ctr, unsigned* __restrict__ L0f, unsigned* __restrict__ L1f,
    float* __restrict__ out, int s,
    unsigned long long* __restrict__ slots_cur,
    unsigned long long* __restrict__ slots_next)
{
  __shared__ float smem[12576];   // union: lstm{xg 4096, red 8320} / fc{part 8448, fin 4128}
  __shared__ int isLast;
  const int bx = blockIdx.x, tid = threadIdx.x, lane = tid & 63, kc = tid >> 6;
  const unsigned stag = (unsigned)(s + 1);

  if (bx < 512){
    // ================= LSTM layer l =================
    const int l  = bx >> 8;
    const int lb = bx & 255;
    const int jt = lb & 31, ko = lb >> 5;
    const float* Wl   = W2T + (size_t)l*1024*GJ;
    const float* bl   = bias2 + l*GJ;
    const float* hsrc = l ? h1s : h0s;
    const float* csrc = l ? c1s : c0s;
    float* hdst = l ? h1d : h0d;
    float* cdst = l ? c1d : c0d;
    float* part = l ? partL1 : partL0;
    unsigned* ct = ctr + l*8;
    const int use_emb = (l==0 && s>0);
    const float* xs = l ? h0d : x0T;            // layer1 x = layer0 output
    float* xg  = smem;          // [128k][32b]
    float* red = smem + 4096;   // [4*32][65]
    const int j = jt*64 + lane;

    // L1 x-half: wait for the two L0 finisher groups covering units ko*128..+128
    if (l == 1 && ko < 4){
      if (tid == 0){
        while (__hip_atomic_load(&L0f[2*ko],   __ATOMIC_RELAXED, __HIP_MEMORY_SCOPE_AGENT) < stag ||
               __hip_atomic_load(&L0f[2*ko+1], __ATOMIC_RELAXED, __HIP_MEMORY_SCOPE_AGENT) < stag)
          __builtin_amdgcn_s_sleep(2);
      }
      __syncthreads();
      __threadfence();          // acquire h0d
    }

    // ---- stage activation chunk into LDS ----
    if (ko >= 4){                                   // recurrent half: h chunk
      const float* base = hsrc + (size_t)(ko-4)*128*BB;
      #pragma unroll
      for (int i=0;i<4;i++)
        *(float4*)&xg[(i*256+tid)*4] = *(const float4*)(base + (size_t)(i*256+tid)*4);
    } else if (!use_emb){                           // x chunk (x0T or layer0 out)
      const float* base = xs + (size_t)ko*128*BB;
      #pragma unroll
      for (int i=0;i<4;i++)
        *(float4*)&xg[(i*256+tid)*4] = *(const float4*)(base + (size_t)(i*256+tid)*4);
    } else {                                        // x = emb[argmax(prev)] gather
      int gb = tid & 31, kt = tid >> 5;             // 32 b x 8 kt (16 k each)
      unsigned long long pk = slots_prev[gb];
      unsigned idx = 0xFFFFFFFFu - (unsigned)(pk & 0xFFFFFFFFull);
      const float* row = emb + (size_t)idx*EMBD + ko*128 + kt*16;
      #pragma unroll
      for (int q4=0;q4<4;q4++){
        float4 r4 = *(const float4*)(row + q4*4);
        xg[(kt*16+q4*4+0)*32 + gb] = r4.x;
        xg[(kt*16+q4*4+1)*32 + gb] = r4.y;
        xg[(kt*16+q4*4+2)*32 + gb] = r4.z;
        xg[(kt*16+q4*4+3)*32 + gb] = r4.w;
      }
    }
    __syncthreads();

    // ---- GEMM: 32 k-iters, LDS broadcast activations ----
    float acc[BB];
    #pragma unroll
    for (int b=0;b<BB;b++) acc[b] = 0.f;

    const float* wp = Wl + (size_t)(ko*128 + kc*32)*GJ + j;
    const float* xb = &xg[(kc*32)*32];
    for (int kk=0;kk<32;kk++){
      float w = wp[(size_t)kk*GJ];                  // coalesced over j
      const float* xr = xb + kk*32;                 // same addr all lanes: broadcast
      #pragma unroll
      for (int bq=0;bq<8;bq++){
        float4 xa = *(const float4*)(xr + bq*4);
        acc[bq*4+0] = fmaf(xa.x, w, acc[bq*4+0]);
        acc[bq*4+1] = fmaf(xa.y, w, acc[bq*4+1]);
        acc[bq*4+2] = fmaf(xa.z, w, acc[bq*4+2]);
        acc[bq*4+3] = fmaf(xa.w, w, acc[bq*4+3]);
      }
    }

    #pragma unroll
    for (int b=0;b<BB;b++) red[(kc*32+b)*65 + lane] = acc[b];
    __syncthreads();

    // ---- reduce 4 kc partials, store part[ko][j][b] fully coalesced ----
    #pragma unroll
    for (int i=0;i<8;i++){
      int idx = i*256 + tid, jl = idx >> 5, b2 = idx & 31;
      float v = red[(0*32+b2)*65 + jl] + red[(1*32+b2)*65 + jl]
              + red[(2*32+b2)*65 + jl] + red[(3*32+b2)*65 + jl];
      part[((size_t)ko*GJ + jt*64 + jl)*BB + b2] = v;
    }
    __threadfence();            // release partials device-wide
    __syncthreads();
    const int ug = jt & 7;      // unit group: 64 units <- jt in {ug,ug+8,ug+16,ug+24}
    if (tid == 0) isLast = (atomicAdd(&ct[ug], 1u) == 31u);
    __syncthreads();
    if (!isLast) return;

    if (tid == 0) ct[ug] = 0;   // re-arm for next step
    __threadfence();            // acquire partials
    const int u0 = ug*64;
    for (int i=0;i<8;i++){
      int cid = i*256 + tid;
      int u = cid >> 5, b2 = cid & 31;
      int uu = u0 + u;
      float gi=0.f, gf=0.f, gg=0.f, go=0.f;
      #pragma unroll
      for (int k2=0;k2<8;k2++){
        const float* pp = part + (size_t)k2*GJ*BB;  // coalesced: b on lanes
        gi += pp[(size_t)(0*512+uu)*BB + b2];
        gf += pp[(size_t)(1*512+uu)*BB + b2];
        gg += pp[(size_t)(2*512+uu)*BB + b2];
        go += pp[(size_t)(3*512+uu)*BB + b2];
      }
      gi += bl[uu]; gf += bl[512+uu]; gg += bl[1024+uu]; go += bl[1536+uu];
      float co = csrc[uu*BB + b2];
      float cn = sigf(gf)*co + sigf(gi)*tanhf(gg);
      float hn = sigf(go)*tanhf(cn);
      cdst[uu*BB + b2] = cn;
      hdst[uu*BB + b2] = hn;
    }
    // release h/c, then publish this unit-group's flag
    __threadfence();
    __syncthreads();
    if (tid == 0)
      __hip_atomic_store(&(l ? L1f : L0f)[ug], stag, __ATOMIC_RELAXED, __HIP_MEMORY_SCOPE_AGENT);
    return;
  }

  // ================= FC + argmax =================
  {
    const int fb = bx - 512;        // 0..249
    if (tid == 0){
      #pragma unroll
      for (int g=0; g<8; g++)
        while (__hip_atomic_load(&L1f[g], __ATOMIC_RELAXED, __HIP_MEMORY_SCOPE_AGENT) < stag)
          __builtin_amdgcn_s_sleep(2);
    }
    __syncthreads();
    __threadfence();                // acquire h1d

    const float* h1T = h1d;
    float* partA = smem;            // [2][128*33]
    float* fin   = smem + 8448;     // [32][129]
    const int c0 = lane*2;
    const int v0 = fb*128 + c0;

    float acc0[BB], acc1[BB];
    #pragma unroll
    for (int b=0;b<BB;b++){ acc0[b] = 0.f; acc1[b] = 0.f; }

    const float2* wp = (const float2*)(fcWT + (size_t)(kc*128)*VV) + (v0 >> 1);
    const float*  hb = h1T + kc*128*BB;
    for (int kk=0;kk<128;kk++){
      float2 w = wp[(size_t)kk*(VV/2)];             // 512B/wave, coalesced over v
      const float* xr = hb + kk*BB;                 // wave-uniform broadcast
      #pragma unroll
      for (int bq=0;bq<8;bq++){
        float4 xa = *(const float4*)(xr + bq*4);
        acc0[bq*4+0] = fmaf(xa.x, w.x, acc0[bq*4+0]);
        acc1[bq*4+0] = fmaf(xa.x, w.y, acc1[bq*4+0]);
        acc0[bq*4+1] = fmaf(xa.y, w.x, acc0[bq*4+1]);
        acc1[bq*4+1] = fmaf(xa.y, w.y, acc1[bq*4+1]);
        acc0[bq*4+2] = fmaf(xa.z, w.x, acc0[bq*4+2]);
        acc1[bq*4+2] = fmaf(xa.z, w.y, acc1[bq*4+2]);
        acc0[bq*4+3] = fmaf(xa.w, w.x, acc0[bq*4+3]);
        acc1[bq*4+3] = fmaf(xa.w, w.y, acc1[bq*4+3]);
      }
    }

    // 2-phase k-reduction in LDS (kc0/1 write, kc2/3 add)
    if (kc < 2){
      float* pp = partA + kc*(128*33);
      #pragma unroll
      for (int b=0;b<BB;b++){ pp[(c0+0)*33 + b] = acc0[b]; pp[(c0+1)*33 + b] = acc1[b]; }
    }
    __syncthreads();
    if (kc >= 2){
      float* pp = partA + (kc-2)*(128*33);
      #pragma unroll
      for (int b=0;b<BB;b++){ pp[(c0+0)*33 + b] += acc0[b]; pp[(c0+1)*33 + b] += acc1[b]; }
    }
    __syncthreads();

    // epilogue: bias, out write (coalesced over v), fin for argmax
    #pragma unroll
    for (int i=0;i<16;i++){
      int cl = (tid & 63) + 64*(i & 1);
      int b  = (tid >> 6) + 4*(i >> 1);
      float val = partA[cl*33 + b] + partA[128*33 + cl*33 + b] + fcb[fb*128 + cl];
      out[(size_t)b*OST + (size_t)s*VV + fb*128 + cl] = val;
      fin[b*129 + cl] = val;
    }
    __syncthreads();

    if (tid < 32){
      int b = tid;
      float best = fin[b*129]; int bv = 0;
      for (int c=1; c<128; c++){                    // ascending: first max wins
        float f = fin[b*129 + c];
        if (f > best){ best = f; bv = c; }
      }
      unsigned long long pk = ((unsigned long long)keyOf(best) << 32)
                            | (unsigned long long)(0xFFFFFFFFu - (unsigned)(fb*128 + bv));
      unsigned long long cur = slots_cur[b];        // guard read (perf only; safe)
      if (pk > cur) atomicMax(slots_cur + b, pk);
    }
    if (fb == 0 && tid >= 64 && tid < 96) slots_next[tid - 64] = 0ull;
  }
}

extern "C" void kernel_launch(void* const* d_in, const int* in_sizes, int n_in,
                              void* d_out, int out_size, void* d_ws, size_t ws_size,
                              hipStream_t stream)
{
  const float* input_seq = (const float*)d_in[0];
  const float* h_enc     = (const float*)d_in[1];
  const float* c_enc     = (const float*)d_in[2];
  const float* Wih       = (const float*)d_in[3];
  const float* Whh       = (const float*)d_in[4];
  const float* bih       = (const float*)d_in[5];
  const float* bhh       = (const float*)d_in[6];
  const float* fcW       = (const float*)d_in[7];
  const float* fcb       = (const float*)d_in[8];
  const float* emb       = (const float*)d_in[9];
  float* out = (float*)d_out;

  char* ws = (char*)d_ws;
  size_t off = 0;
  auto alloc = [&](size_t bytes)->void*{
    void* p = ws + off; off += (bytes + 255) & ~(size_t)255; return p;
  };
  float* fcWT  = (float*)alloc((size_t)512*VV*4);        // [k][v]
  float* W2T   = (float*)alloc((size_t)2*1024*GJ*4);     // [l][k][j]
  float* bias2 = (float*)alloc((size_t)2*GJ*4);
  float* x0T   = (float*)alloc((size_t)512*BB*4);        // [k][b]
  float* hT    = (float*)alloc((size_t)2*2*512*BB*4);    // [parity][l][u][b]
  float* cT    = (float*)alloc((size_t)2*2*512*BB*4);
  float* partL0= (float*)alloc((size_t)8*GJ*BB*4);       // [ko][j][b]
  float* partL1= (float*)alloc((size_t)8*GJ*BB*4);
  unsigned long long* slots = (unsigned long long*)alloc(2*BB*8); // [parity][b]
  unsigned* ctr  = (unsigned*)alloc(16*4);               // [layer][ug]
  unsigned* L0f  = (unsigned*)alloc(8*4);                // monotone step flags
  unsigned* L1f  = (unsigned*)alloc(8*4);

  hipMemsetAsync(slots, 0, 2*BB*8, stream);
  hipMemsetAsync(ctr,   0, 16*4,   stream);
  hipMemsetAsync(L0f,   0, 8*4,    stream);
  hipMemsetAsync(L1f,   0, 8*4,    stream);

  dim3 tb(256);
  ktran<<<dim3(16,1000), tb, 0, stream>>>(fcW, fcWT, VV, 512, VV);
  ktran<<<dim3(16,64), tb, 0, stream>>>(Wih,            W2T,                         GJ, 512, GJ);
  ktran<<<dim3(16,64), tb, 0, stream>>>(Whh,            W2T + (size_t)512*GJ,        GJ, 512, GJ);
  ktran<<<dim3(16,64), tb, 0, stream>>>(Wih + (size_t)GJ*512, W2T + (size_t)1024*GJ, GJ, 512, GJ);
  ktran<<<dim3(16,64), tb, 0, stream>>>(Whh + (size_t)GJ*512, W2T + (size_t)1024*GJ + (size_t)512*GJ, GJ, 512, GJ);
  kbias<<<16, tb, 0, stream>>>(bih, bhh, bias2);
  kinit<<<320, tb, 0, stream>>>(input_seq, h_enc, c_enc, x0T, hT, cT);

  const size_t LSZ = 512*BB;
  for (int s=0; s<SS; s++){
    int p = s & 1, q = p ^ 1;
    float* h0s = hT + (size_t)(p*2+0)*LSZ;  float* h0d = hT + (size_t)(q*2+0)*LSZ;
    float* h1s = hT + (size_t)(p*2+1)*LSZ;  float* h1d = hT + (size_t)(q*2+1)*LSZ;
    float* c0s = cT + (size_t)(p*2+0)*LSZ;  float* c0d = cT + (size_t)(q*2+0)*LSZ;
    float* c1s = cT + (size_t)(p*2+1)*LSZ;  float* c1d = cT + (size_t)(q*2+1)*LSZ;

    kstep<<<762, tb, 0, stream>>>(W2T, bias2, x0T,
        (s>0) ? (slots + (size_t)((s-1)&1)*BB) : nullptr, emb,
        fcWT, fcb,
        h0s, c0s, h0d, c0d, h1s, c1s, h1d, c1d,
        partL0, partL1, ctr, L0f, L1f, out, s,
        slots + (size_t)(s&1)*BB, slots + (size_t)((s+1)&1)*BB);
  }
}

// Round 5
// 7732.522 us; speedup vs baseline: 2.2677x; 1.2128x over previous
//
#include <hip/hip_runtime.h>
#include <math.h>

// LSTMDecoder: VOCAB=32000, EMB=512, HID=512, LAYERS=2, BATCH=32, SEQ=64
// Round 6: r2 3-launch structure (verified 8483us) + kfc LDS-staged h.
//  - kfc: stage full h (512x32 = 64KB, exactly max LDS) per block; inner loop
//    reads h via broadcast ds_read_b128 instead of 1024 global L2 loads/thread;
//    part/fin alias the h region (only touched after post-GEMM barrier);
//    unroll 16 keeps ~16 weight loads in flight over LLC/HBM latency.
//  - klstm + launcher byte-identical to verified r2 -> delta attributes to FC.
//  - Refuted: r3 mega (17.5ms, barriers kill overlap), r4 block512 (10.4ms),
//    r5 dataflow-fused step (9.4ms). Phases are latency-bound internally.

#define BB   32
#define EMBD 512
#define HIDD 512
#define VV   32000
#define SS   64
#define GJ   2048          // 4*HID
#define OST  (SS*VV)       // out stride per batch

__device__ __forceinline__ float sigf(float x){ return 1.0f/(1.0f + expf(-x)); }
__device__ __forceinline__ unsigned keyOf(float f){
  unsigned u = __float_as_uint(f);
  return (u & 0x80000000u) ? ~u : (u | 0x80000000u);   // monotone float->uint
}

// generic 32x32 tiled transpose: dst[c*dstLd + r] = src[r*C + c]
__global__ void ktran(const float* __restrict__ src, float* __restrict__ dst,
                      int R, int C, int dstLd)
{
  __shared__ float t[32][33];
  int c0 = blockIdx.x*32, r0 = blockIdx.y*32;
  int tx = threadIdx.x & 31, ty = threadIdx.x >> 5;
  #pragma unroll
  for (int i=0;i<4;i++) t[ty+i*8][tx] = src[(size_t)(r0+ty+i*8)*C + (c0+tx)];
  __syncthreads();
  #pragma unroll
  for (int i=0;i<4;i++) dst[(size_t)(c0+ty+i*8)*dstLd + (r0+tx)] = t[tx][ty+i*8];
}

__global__ void kbias(const float* __restrict__ bih, const float* __restrict__ bhh,
                      float* __restrict__ bias2){
  int i = blockIdx.x*256 + threadIdx.x;
  if (i < 2*GJ) bias2[i] = bih[i] + bhh[i];
}

// x0T[k][b] = input_seq[b][0][k];  hT/cT parity0: [l][u][b] = h_encode[l][b][u]
__global__ void kinit(const float* __restrict__ iseq, const float* __restrict__ he,
                      const float* __restrict__ ce, float* __restrict__ x0T,
                      float* __restrict__ hT, float* __restrict__ cT)
{
  int tid = blockIdx.x*256 + threadIdx.x;
  if (tid < 16384){
    int k = tid>>5, b = tid&31;
    x0T[tid] = iseq[(size_t)b*(SS*EMBD) + k];
  } else if (tid < 49152){
    int t2 = tid - 16384;
    int l = t2>>14, r = t2&16383, u = r>>5, b = r&31;
    hT[t2] = he[(size_t)(l*BB + b)*HIDD + u];
  } else if (tid < 81920){
    int t2 = tid - 49152;
    int l = t2>>14, r = t2&16383, u = r>>5, b = r&31;
    cT[t2] = ce[(size_t)(l*BB + b)*HIDD + u];
  }
}

// One LSTM layer. grid=256: jt=bx&31 (64-wide j tile), ko=bx>>5 (128-wide k chunk
// of K=1024=[x(512);h(512)]). block=256=4 waves (kc: 32-wide k subchunk).
// Activation chunk staged in LDS; inner reads are wave-uniform broadcasts.
// Partials -> part[ko][j][b] (coalesced both ways); ticket finisher does cell.
__global__ __launch_bounds__(256) void klstm(
    const float* __restrict__ W2T, const float* __restrict__ bias2,
    const float* __restrict__ xsrc, const unsigned long long* __restrict__ slots_prev,
    const float* __restrict__ emb,
    const float* __restrict__ hsrc, const float* __restrict__ csrc,
    float* __restrict__ hdst, float* __restrict__ cdst,
    float* __restrict__ part, unsigned* __restrict__ ctr, int use_emb)
{
  __shared__ float xg[128*32];      // block's 128-k x 32-b activation chunk
  __shared__ float red[4*32*65];    // [kc*32+b][j], pad 65 vs bank conflicts
  __shared__ int isLast;
  int bx = blockIdx.x;
  int jt = bx & 31, ko = bx >> 5;
  int tid = threadIdx.x, lane = tid & 63, kc = tid >> 6;
  int j = jt*64 + lane;

  // ---- stage activation chunk into LDS ----
  if (ko >= 4){                                   // recurrent half: h chunk
    const float* base = hsrc + (size_t)(ko-4)*128*BB;
    #pragma unroll
    for (int i=0;i<4;i++)
      *(float4*)&xg[(i*256+tid)*4] = *(const float4*)(base + (size_t)(i*256+tid)*4);
  } else if (!use_emb){                           // x chunk (x0T or prev-layer hT)
    const float* base = xsrc + (size_t)ko*128*BB;
    #pragma unroll
    for (int i=0;i<4;i++)
      *(float4*)&xg[(i*256+tid)*4] = *(const float4*)(base + (size_t)(i*256+tid)*4);
  } else {                                        // x = emb[argmax(prev)] gather
    int gb = tid & 31, kt = tid >> 5;             // 32 b x 8 kt (16 k each)
    unsigned long long pk = slots_prev[gb];
    unsigned idx = 0xFFFFFFFFu - (unsigned)(pk & 0xFFFFFFFFull);
    const float* row = emb + (size_t)idx*EMBD + ko*128 + kt*16;
    #pragma unroll
    for (int q=0;q<4;q++){
      float4 r4 = *(const float4*)(row + q*4);
      xg[(kt*16+q*4+0)*32 + gb] = r4.x;
      xg[(kt*16+q*4+1)*32 + gb] = r4.y;
      xg[(kt*16+q*4+2)*32 + gb] = r4.z;
      xg[(kt*16+q*4+3)*32 + gb] = r4.w;
    }
  }
  __syncthreads();

  // ---- GEMM: 32 k-iters, LDS broadcast activations ----
  float acc[BB];
  #pragma unroll
  for (int b=0;b<BB;b++) acc[b] = 0.f;

  const float* wp = W2T + (size_t)(ko*128 + kc*32)*GJ + j;
  const float* xb = &xg[(kc*32)*32];
  for (int kk=0;kk<32;kk++){
    float w = wp[(size_t)kk*GJ];                  // coalesced over j
    const float* xr = xb + kk*32;                 // same addr all lanes: broadcast
    #pragma unroll
    for (int bq=0;bq<8;bq++){
      float4 xa = *(const float4*)(xr + bq*4);
      acc[bq*4+0] = fmaf(xa.x, w, acc[bq*4+0]);
      acc[bq*4+1] = fmaf(xa.y, w, acc[bq*4+1]);
      acc[bq*4+2] = fmaf(xa.z, w, acc[bq*4+2]);
      acc[bq*4+3] = fmaf(xa.w, w, acc[bq*4+3]);
    }
  }

  #pragma unroll
  for (int b=0;b<BB;b++) red[(kc*32+b)*65 + lane] = acc[b];
  __syncthreads();

  // ---- reduce 4 kc partials, store part[ko][j][b] fully coalesced ----
  #pragma unroll
  for (int i=0;i<8;i++){
    int idx = i*256 + tid, jl = idx >> 5, b2 = idx & 31;
    float v = red[(0*32+b2)*65 + jl] + red[(1*32+b2)*65 + jl]
            + red[(2*32+b2)*65 + jl] + red[(3*32+b2)*65 + jl];
    part[((size_t)ko*GJ + jt*64 + jl)*BB + b2] = v;
  }
  __threadfence();            // release partials device-wide
  __syncthreads();
  int ug = jt & 7;            // unit group: 64 units <- jt in {ug,ug+8,ug+16,ug+24}
  if (tid == 0) isLast = (atomicAdd(&ctr[ug], 1u) == 31u);
  __syncthreads();
  if (!isLast) return;

  if (tid == 0) ctr[ug] = 0;  // re-arm for next launch
  __threadfence();            // acquire (kernel also starts w/ acquire next launch)
  const int u0 = ug*64;
  for (int i=0;i<8;i++){
    int cid = i*256 + tid;
    int u = cid >> 5, b2 = cid & 31;
    int uu = u0 + u;
    float gi=0.f, gf=0.f, gg=0.f, go=0.f;
    #pragma unroll
    for (int k2=0;k2<8;k2++){
      const float* pp = part + (size_t)k2*GJ*BB;  // coalesced: b on lanes
      gi += pp[(size_t)(0*512+uu)*BB + b2];
      gf += pp[(size_t)(1*512+uu)*BB + b2];
      gg += pp[(size_t)(2*512+uu)*BB + b2];
      go += pp[(size_t)(3*512+uu)*BB + b2];
    }
    gi += bias2[uu]; gf += bias2[512+uu]; gg += bias2[1024+uu]; go += bias2[1536+uu];
    float co = csrc[uu*BB + b2];
    float cn = sigf(gf)*co + sigf(gi)*tanhf(gg);
    float hn = sigf(go)*tanhf(cn);
    cdst[uu*BB + b2] = cn;
    hdst[uu*BB + b2] = hn;
  }
}

// FC + argmax. grid=250 (128-col tiles), block=256=4 waves.
// h staged ONCE in LDS (64KB = full 512x32); part/fin alias the h region
// (safe: only touched after the post-GEMM barrier). Lane owns 2 cols
// (float2 weights, 512B/wave); kc=tid>>6 is a 128-k split; unroll 16 keeps
// weight loads in flight. 2-phase LDS reduction, then argmax.
__global__ __launch_bounds__(256) void kfc(
    const float* __restrict__ fcWT, const float* __restrict__ fcb,
    const float* __restrict__ h1T, float* __restrict__ out, int s,
    unsigned long long* __restrict__ slots_cur,
    unsigned long long* __restrict__ slots_next)
{
  __shared__ float smem[16384];     // 64KB: hs[512][32] / {part[2][128*33], fin[32*129]}
  float* part0 = smem;              // 4224 floats
  float* part1 = smem + 4224;       // 4224 floats
  float* fin   = smem + 8448;       // 4128 floats
  int bx = blockIdx.x;
  int tid = threadIdx.x, lane = tid & 63, kc = tid >> 6;
  int c0 = lane*2;
  int v0 = bx*128 + c0;

  // ---- stage full h (512x32 floats) into LDS, coalesced float4 ----
  #pragma unroll
  for (int i=0;i<16;i++)
    ((float4*)smem)[i*256 + tid] = ((const float4*)h1T)[i*256 + tid];
  __syncthreads();

  float acc0[BB], acc1[BB];
  #pragma unroll
  for (int b=0;b<BB;b++){ acc0[b] = 0.f; acc1[b] = 0.f; }

  const float2* wp = (const float2*)(fcWT + (size_t)(kc*128)*VV) + (v0 >> 1);
  const float*  hx = smem + (kc*128)*32;
  #pragma unroll 16
  for (int kk=0;kk<128;kk++){
    float2 w = wp[(size_t)kk*(VV/2)];             // 512B/wave, coalesced over v
    const float* xr = hx + kk*32;                 // LDS broadcast (same addr all lanes)
    #pragma unroll
    for (int bq=0;bq<8;bq++){
      float4 xa = *(const float4*)(xr + bq*4);
      acc0[bq*4+0] = fmaf(xa.x, w.x, acc0[bq*4+0]);
      acc1[bq*4+0] = fmaf(xa.x, w.y, acc1[bq*4+0]);
      acc0[bq*4+1] = fmaf(xa.y, w.x, acc0[bq*4+1]);
      acc1[bq*4+1] = fmaf(xa.y, w.y, acc1[bq*4+1]);
      acc0[bq*4+2] = fmaf(xa.z, w.x, acc0[bq*4+2]);
      acc1[bq*4+2] = fmaf(xa.z, w.y, acc1[bq*4+2]);
      acc0[bq*4+3] = fmaf(xa.w, w.x, acc0[bq*4+3]);
      acc1[bq*4+3] = fmaf(xa.w, w.y, acc1[bq*4+3]);
    }
  }
  __syncthreads();              // all GEMM reads of hs done before part aliases it

  // 2-phase k-reduction in LDS (kc0/1 write, kc2/3 add)
  if (kc < 2){
    float* p = (kc == 0) ? part0 : part1;
    #pragma unroll
    for (int b=0;b<BB;b++){ p[(c0+0)*33 + b] = acc0[b]; p[(c0+1)*33 + b] = acc1[b]; }
  }
  __syncthreads();
  if (kc >= 2){
    float* p = (kc == 2) ? part0 : part1;
    #pragma unroll
    for (int b=0;b<BB;b++){ p[(c0+0)*33 + b] += acc0[b]; p[(c0+1)*33 + b] += acc1[b]; }
  }
  __syncthreads();

  // epilogue: bias, out write (coalesced over v), fin for argmax
  #pragma unroll
  for (int i=0;i<16;i++){
    int cl = (tid & 63) + 64*(i & 1);
    int b  = (tid >> 6) + 4*(i >> 1);
    float val = part0[cl*33 + b] + part1[cl*33 + b] + fcb[bx*128 + cl];
    out[(size_t)b*OST + (size_t)s*VV + bx*128 + cl] = val;
    fin[b*129 + cl] = val;
  }
  __syncthreads();

  if (tid < 32){
    int b = tid;
    float best = fin[b*129]; int bv = 0;
    for (int c=1; c<128; c++){                    // ascending: first max wins
      float f = fin[b*129 + c];
      if (f > best){ best = f; bv = c; }
    }
    unsigned long long pk = ((unsigned long long)keyOf(best) << 32)
                          | (unsigned long long)(0xFFFFFFFFu - (unsigned)(bx*128 + bv));
    unsigned long long cur = slots_cur[b];        // guard read (perf only; safe)
    if (pk > cur) atomicMax(slots_cur + b, pk);
  }
  if (bx == 0 && tid >= 64 && tid < 96) slots_next[tid - 64] = 0ull;
}

extern "C" void kernel_launch(void* const* d_in, const int* in_sizes, int n_in,
                              void* d_out, int out_size, void* d_ws, size_t ws_size,
                              hipStream_t stream)
{
  const float* input_seq = (const float*)d_in[0];
  const float* h_enc     = (const float*)d_in[1];
  const float* c_enc     = (const float*)d_in[2];
  const float* Wih       = (const float*)d_in[3];
  const float* Whh       = (const float*)d_in[4];
  const float* bih       = (const float*)d_in[5];
  const float* bhh       = (const float*)d_in[6];
  const float* fcW       = (const float*)d_in[7];
  const float* fcb       = (const float*)d_in[8];
  const float* emb       = (const float*)d_in[9];
  float* out = (float*)d_out;

  char* ws = (char*)d_ws;
  size_t off = 0;
  auto alloc = [&](size_t bytes)->void*{
    void* p = ws + off; off += (bytes + 255) & ~(size_t)255; return p;
  };
  float* fcWT  = (float*)alloc((size_t)512*VV*4);        // [k][v]
  float* W2T   = (float*)alloc((size_t)2*1024*GJ*4);     // [l][k][j]
  float* bias2 = (float*)alloc((size_t)2*GJ*4);
  float* x0T   = (float*)alloc((size_t)512*BB*4);        // [k][b]
  float* hT    = (float*)alloc((size_t)2*2*512*BB*4);    // [parity][l][u][b]
  float* cT    = (float*)alloc((size_t)2*2*512*BB*4);
  float* partL0= (float*)alloc((size_t)8*GJ*BB*4);       // [ko][j][b]
  float* partL1= (float*)alloc((size_t)8*GJ*BB*4);
  unsigned long long* slots = (unsigned long long*)alloc(2*BB*8); // [parity][b]
  unsigned* ctr = (unsigned*)alloc(16*4);                // [layer][ug]

  hipMemsetAsync(slots, 0, 2*BB*8, stream);
  hipMemsetAsync(ctr,   0, 16*4,   stream);

  dim3 tb(256);
  ktran<<<dim3(16,1000), tb, 0, stream>>>(fcW, fcWT, VV, 512, VV);
  ktran<<<dim3(16,64), tb, 0, stream>>>(Wih,            W2T,                         GJ, 512, GJ);
  ktran<<<dim3(16,64), tb, 0, stream>>>(Whh,            W2T + (size_t)512*GJ,        GJ, 512, GJ);
  ktran<<<dim3(16,64), tb, 0, stream>>>(Wih + (size_t)GJ*512, W2T + (size_t)1024*GJ, GJ, 512, GJ);
  ktran<<<dim3(16,64), tb, 0, stream>>>(Whh + (size_t)GJ*512, W2T + (size_t)1024*GJ + (size_t)512*GJ, GJ, 512, GJ);
  kbias<<<16, tb, 0, stream>>>(bih, bhh, bias2);
  kinit<<<320, tb, 0, stream>>>(input_seq, h_enc, c_enc, x0T, hT, cT);

  const size_t LSZ = 512*BB;
  for (int s=0; s<SS; s++){
    int p = s & 1, q = p ^ 1;
    float* h0s = hT + (size_t)(p*2+0)*LSZ;  float* h0d = hT + (size_t)(q*2+0)*LSZ;
    float* h1s = hT + (size_t)(p*2+1)*LSZ;  float* h1d = hT + (size_t)(q*2+1)*LSZ;
    float* c0s = cT + (size_t)(p*2+0)*LSZ;  float* c0d = cT + (size_t)(q*2+0)*LSZ;
    float* c1s = cT + (size_t)(p*2+1)*LSZ;  float* c1d = cT + (size_t)(q*2+1)*LSZ;

    klstm<<<256, tb, 0, stream>>>(W2T, bias2,
        (s==0) ? x0T : nullptr,
        (s>0) ? (slots + ((s-1)&1)*BB) : nullptr,
        emb, h0s, c0s, h0d, c0d, partL0, ctr, (s>0) ? 1 : 0);
    klstm<<<256, tb, 0, stream>>>(W2T + (size_t)1024*GJ, bias2 + GJ,
        h0d, nullptr, emb, h1s, c1s, h1d, c1d, partL1, ctr + 8, 0);
    kfc<<<250, tb, 0, stream>>>(fcWT, fcb, h1d, out, s,
        slots + (s&1)*BB, slots + ((s+1)&1)*BB);
  }
}